// Round 1
// baseline (248.920 us; speedup 1.0000x reference)
//
#include <hip/hip_runtime.h>
#include <hip/hip_bf16.h>
#include <stdint.h>

#define N_TOK 8192
#define DIM   1024
#define NEXP  8
#define CAP   1024

typedef __attribute__((ext_vector_type(8))) short bf16x8;
typedef __attribute__((ext_vector_type(4))) float f32x4;

static __device__ __forceinline__ unsigned short f2bf(float f) {
  unsigned int u = __float_as_uint(f);
  u += 0x7FFFu + ((u >> 16) & 1u);          // round-to-nearest-even
  return (unsigned short)(u >> 16);
}

// async global->LDS, 16B per lane. LDS dest must be wave-uniform base (HW adds lane*16).
static __device__ __forceinline__ void gld_lds16(const void* g, void* l) {
  __builtin_amdgcn_global_load_lds(
      (__attribute__((address_space(1))) void*)(uintptr_t)g,
      (__attribute__((address_space(3))) void*)(unsigned int)(uintptr_t)l,
      16, 0, 0);
}

// ---------------- Router: logits = x@Wr + br ; gate = max softmax prob ; idx = argmax ----
__global__ void router_kernel(const float* __restrict__ x, const float* __restrict__ Wr,
                              const float* __restrict__ br, float* __restrict__ gate,
                              int* __restrict__ idxs) {
  const int wid  = (blockIdx.x * blockDim.x + threadIdx.x) >> 6;   // token id (1 wave/token)
  const int lane = threadIdx.x & 63;
  const float* xr = x + (size_t)wid * DIM;
  double acc[8] = {0,0,0,0,0,0,0,0};
  #pragma unroll 4
  for (int j = 0; j < 16; ++j) {
    const int d = j * 64 + lane;
    const double xv = (double)xr[d];
    const float4 wa = *(const float4*)(Wr + d * 8);
    const float4 wb = *(const float4*)(Wr + d * 8 + 4);
    acc[0] += xv * (double)wa.x;  acc[1] += xv * (double)wa.y;
    acc[2] += xv * (double)wa.z;  acc[3] += xv * (double)wa.w;
    acc[4] += xv * (double)wb.x;  acc[5] += xv * (double)wb.y;
    acc[6] += xv * (double)wb.z;  acc[7] += xv * (double)wb.w;
  }
  #pragma unroll
  for (int off = 1; off < 64; off <<= 1) {
    #pragma unroll
    for (int e = 0; e < 8; ++e) acc[e] += __shfl_xor(acc[e], off);
  }
  if (lane == 0) {
    double lg[8];
    #pragma unroll
    for (int e = 0; e < 8; ++e) lg[e] = acc[e] + (double)br[e];
    int best = 0; double bm = lg[0];
    #pragma unroll
    for (int e = 1; e < 8; ++e) { if (lg[e] > bm) { bm = lg[e]; best = e; } }  // first-wins ties
    double s = 0.0;
    #pragma unroll
    for (int e = 0; e < 8; ++e) s += exp(lg[e] - bm);
    gate[wid] = (float)(1.0 / s);   // max softmax prob
    idxs[wid] = best;
  }
}

// ---------------- Ordered per-expert position scan (single block, 1024 thr, 8 tok/thr) ----
__global__ void scan_kernel(const int* __restrict__ idxs, int* __restrict__ slot_token) {
  __shared__ int wtot[16][8];
  const int t = threadIdx.x, lane = t & 63, w = t >> 6;
  int myidx[8];
  #pragma unroll
  for (int j = 0; j < 8; ++j) myidx[j] = idxs[t * 8 + j];
  int cnt[8], incl[8];
  #pragma unroll
  for (int e = 0; e < 8; ++e) {
    int c = 0;
    #pragma unroll
    for (int j = 0; j < 8; ++j) c += (myidx[j] == e) ? 1 : 0;
    cnt[e] = c;
    int v = c;
    #pragma unroll
    for (int off = 1; off < 64; off <<= 1) {
      int u = __shfl_up(v, off);
      if (lane >= off) v += u;
    }
    incl[e] = v;                       // inclusive within-wave prefix
  }
  if (lane == 63) {
    #pragma unroll
    for (int e = 0; e < 8; ++e) wtot[w][e] = incl[e];
  }
  __syncthreads();
  if (t == 0) {                        // serial exclusive scan over 16 wave totals
    int run[8] = {0,0,0,0,0,0,0,0};
    for (int ww = 0; ww < 16; ++ww) {
      #pragma unroll
      for (int e = 0; e < 8; ++e) {
        int tmp = wtot[ww][e]; wtot[ww][e] = run[e]; run[e] += tmp;
      }
    }
  }
  __syncthreads();
  #pragma unroll
  for (int e = 0; e < 8; ++e) {
    int r = wtot[w][e] + incl[e] - cnt[e];   // tokens of expert e before my chunk
    #pragma unroll
    for (int j = 0; j < 8; ++j) {
      if (myidx[j] == e) {
        ++r;                                  // 1-based pos (slot 0 never used)
        if (r < CAP) slot_token[e * CAP + r] = t * 8 + j;   // pos<C kept
      }
    }
  }
}

// ---------------- Gather: Xe[slot,:] = bf16(gate[n] * x[n,:]) ----------------------------
__global__ void gather_kernel(const float* __restrict__ x, const float* __restrict__ gate,
                              const int* __restrict__ slot_token,
                              unsigned short* __restrict__ Xe) {
  const int s = blockIdx.x;
  const int n = slot_token[s];
  if (n < 0) return;                    // empty slot: row stays poison, never reaches output
  const float g = gate[n];
  const int t = threadIdx.x;            // 256 threads * float4 = 1024 elems
  const float4 v = ((const float4*)(x + (size_t)n * DIM))[t];
  ushort4 o;
  o.x = f2bf(v.x * g); o.y = f2bf(v.y * g); o.z = f2bf(v.z * g); o.w = f2bf(v.w * g);
  ((ushort4*)(Xe + (size_t)s * DIM))[t] = o;
}

// ---------------- Weights: fp32 [K,N] -> bf16 transposed [N,K] (B^T layout), per expert ---
__global__ void wt_kernel(const float* __restrict__ W1, const float* __restrict__ W2,
                          unsigned short* __restrict__ W1T, unsigned short* __restrict__ W2T) {
  __shared__ float tile[32][33];
  const int mi = blockIdx.y;                        // 0..7: W1 expert, 8..15: W2 expert
  const int tz = blockIdx.x;
  const int tr = tz >> 5, tc = tz & 31;             // 32x32 tiles over 1024x1024
  const float* src = (mi < 8) ? (W1 + (size_t)mi * DIM * DIM)
                              : (W2 + (size_t)(mi - 8) * DIM * DIM);
  unsigned short* dst = (mi < 8) ? (W1T + (size_t)mi * DIM * DIM)
                                 : (W2T + (size_t)(mi - 8) * DIM * DIM);
  const int t = threadIdx.x;
  const int row = t >> 3;
  const int cg  = (t & 7) * 4;
  const float4 v = *(const float4*)(src + (size_t)(tr * 32 + row) * DIM + tc * 32 + cg);
  tile[row][cg + 0] = v.x; tile[row][cg + 1] = v.y;
  tile[row][cg + 2] = v.z; tile[row][cg + 3] = v.w;
  __syncthreads();
  ushort4 o;
  o.x = f2bf(tile[cg + 0][row]); o.y = f2bf(tile[cg + 1][row]);
  o.z = f2bf(tile[cg + 2][row]); o.w = f2bf(tile[cg + 3][row]);
  *(ushort4*)(dst + (size_t)(tc * 32 + row) * DIM + tr * 32 + cg) = o;
}

// ---------------- Grouped GEMM, 128x128 tile, BK=32, 16x16x32 bf16 MFMA ------------------
// OP==1: H = relu(Xe @ W1 + b1) -> bf16.   OP==2: out[token] = gate*(H @ W2 + b2) scatter.
template <int OP>
__global__ __launch_bounds__(256)
void gemm_kernel(const unsigned short* __restrict__ A,    // [E*CAP][DIM] bf16
                 const unsigned short* __restrict__ Bt,   // [E][DIM][DIM] bf16 (B^T rows=N)
                 const float* __restrict__ bias,          // [E][DIM]
                 const int* __restrict__ slot_token,      // OP==2
                 const float* __restrict__ gate,          // OP==2
                 unsigned short* __restrict__ Hout,       // OP==1
                 float* __restrict__ Cout)                // OP==2
{
  __shared__ unsigned short Asub[128 * 32];
  __shared__ unsigned short Bsub[128 * 32];
  const int e  = blockIdx.y;
  const int bm = blockIdx.x >> 3;
  const int bn = blockIdx.x & 7;
  const int tid = threadIdx.x, lane = tid & 63, w = tid >> 6;
  const int wr = w >> 1, wc = w & 1;

  const unsigned short* Ae = A  + (size_t)(e * CAP + bm * 128) * DIM;
  const unsigned short* Be = Bt + (size_t)e * DIM * DIM + (size_t)(bn * 128) * DIM;

  const int srow = lane >> 2;           // staging: 16 rows per 1KB chunk, 4 lanes/row
  const int scol = (lane & 3) * 8;      // 8 bf16 = 16B per lane
  const int lrow = lane & 15;
  const int kof  = (lane >> 4) * 8;

  f32x4 acc[4][4] = {};

  for (int kt = 0; kt < 32; ++kt) {
    const int k0 = kt * 32;
    #pragma unroll
    for (int c = 0; c < 2; ++c) {
      const int chunk = w + c * 4;                       // wave-uniform
      const int r = chunk * 16 + srow;
      gld_lds16(Ae + (size_t)r * DIM + k0 + scol, &Asub[chunk * 512]);
      gld_lds16(Be + (size_t)r * DIM + k0 + scol, &Bsub[chunk * 512]);
    }
    __syncthreads();                                     // drains vmcnt: tiles ready
    bf16x8 af[4], bfr[4];
    #pragma unroll
    for (int m = 0; m < 4; ++m)
      af[m] = *(const bf16x8*)&Asub[(wr * 64 + m * 16 + lrow) * 32 + kof];
    #pragma unroll
    for (int n = 0; n < 4; ++n)
      bfr[n] = *(const bf16x8*)&Bsub[(wc * 64 + n * 16 + lrow) * 32 + kof];
    #pragma unroll
    for (int m = 0; m < 4; ++m)
      #pragma unroll
      for (int n = 0; n < 4; ++n)
        acc[m][n] = __builtin_amdgcn_mfma_f32_16x16x32_bf16(af[m], bfr[n], acc[m][n], 0, 0, 0);
    __syncthreads();                                     // protect LDS for next stage
  }

  if (OP == 1) {
    #pragma unroll
    for (int n = 0; n < 4; ++n) {
      const int col = bn * 128 + wc * 64 + n * 16 + lrow;
      const float bv = bias[e * DIM + col];
      #pragma unroll
      for (int m = 0; m < 4; ++m) {
        const int r0 = bm * 128 + wr * 64 + m * 16 + (lane >> 4) * 4;
        #pragma unroll
        for (int i = 0; i < 4; ++i) {
          float v = acc[m][n][i] + bv;
          v = v > 0.0f ? v : 0.0f;
          Hout[(size_t)(e * CAP + r0 + i) * DIM + col] = f2bf(v);
        }
      }
    }
  } else {
    float bv[4];
    #pragma unroll
    for (int n = 0; n < 4; ++n)
      bv[n] = bias[e * DIM + bn * 128 + wc * 64 + n * 16 + lrow];
    #pragma unroll
    for (int m = 0; m < 4; ++m) {
      const int r0 = bm * 128 + wr * 64 + m * 16 + (lane >> 4) * 4;
      #pragma unroll
      for (int i = 0; i < 4; ++i) {
        const int tok = slot_token[e * CAP + r0 + i];
        if (tok >= 0) {
          const float g = gate[tok];
          float* orow = Cout + (size_t)tok * DIM;
          #pragma unroll
          for (int n = 0; n < 4; ++n) {
            const int col = bn * 128 + wc * 64 + n * 16 + lrow;
            orow[col] = g * (acc[m][n][i] + bv[n]);
          }
        }
      }
    }
  }
}

extern "C" void kernel_launch(void* const* d_in, const int* in_sizes, int n_in,
                              void* d_out, int out_size, void* d_ws, size_t ws_size,
                              hipStream_t stream) {
  const float* x  = (const float*)d_in[0];
  const float* Wr = (const float*)d_in[1];
  const float* br = (const float*)d_in[2];
  const float* W1 = (const float*)d_in[3];
  const float* b1 = (const float*)d_in[4];
  const float* W2 = (const float*)d_in[5];
  const float* b2 = (const float*)d_in[6];
  float* out = (float*)d_out;

  char* ws = (char*)d_ws;
  unsigned short* Xe  = (unsigned short*)(ws);                                  // 16 MB
  unsigned short* Hh  = (unsigned short*)(ws + (size_t)16 * 1024 * 1024);       // 16 MB
  unsigned short* W1T = (unsigned short*)(ws + (size_t)32 * 1024 * 1024);       // 16 MB
  unsigned short* W2T = (unsigned short*)(ws + (size_t)48 * 1024 * 1024);       // 16 MB
  float* gate     = (float*)(ws + (size_t)64 * 1024 * 1024);                    // 32 KB
  int*   idxs     = (int*)  (ws + (size_t)64 * 1024 * 1024 + 32768);            // 32 KB
  int*   slot_tok = (int*)  (ws + (size_t)64 * 1024 * 1024 + 65536);            // 32 KB

  hipMemsetAsync(out, 0, (size_t)N_TOK * DIM * sizeof(float), stream);   // dropped tokens -> 0
  hipMemsetAsync(slot_tok, 0xFF, NEXP * CAP * sizeof(int), stream);      // all slots empty (-1)

  router_kernel<<<2048, 256, 0, stream>>>(x, Wr, br, gate, idxs);
  scan_kernel<<<1, 1024, 0, stream>>>(idxs, slot_tok);
  gather_kernel<<<N_TOK, 256, 0, stream>>>(x, gate, slot_tok, Xe);
  wt_kernel<<<dim3(1024, 16), 256, 0, stream>>>(W1, W2, W1T, W2T);
  gemm_kernel<1><<<dim3(64, NEXP), 256, 0, stream>>>(Xe, W1T, b1, nullptr, nullptr, Hh, nullptr);
  gemm_kernel<2><<<dim3(64, NEXP), 256, 0, stream>>>(Hh, W2T, b2, slot_tok, gate, nullptr, out);
}

// Round 2
// 245.116 us; speedup vs baseline: 1.0155x; 1.0155x over previous
//
#include <hip/hip_runtime.h>
#include <hip/hip_bf16.h>
#include <stdint.h>

#define N_TOK 8192
#define DIM   1024
#define NEXP  8
#define CAP   1024

typedef __attribute__((ext_vector_type(8))) short bf16x8;
typedef __attribute__((ext_vector_type(4))) float f32x4;

static __device__ __forceinline__ unsigned short f2bf(float f) {
  unsigned int u = __float_as_uint(f);
  u += 0x7FFFu + ((u >> 16) & 1u);          // round-to-nearest-even
  return (unsigned short)(u >> 16);
}

// async global->LDS, 16B per lane. LDS dest must be wave-uniform base (HW adds lane*16).
static __device__ __forceinline__ void gld_lds16(const void* g, void* l) {
  __builtin_amdgcn_global_load_lds(
      (__attribute__((address_space(1))) void*)(uintptr_t)g,
      (__attribute__((address_space(3))) void*)(unsigned int)(uintptr_t)l,
      16, 0, 0);
}

// ---------------- Router: logits = x@Wr + br ; gate = max softmax prob ; idx = argmax ----
__global__ void router_kernel(const float* __restrict__ x, const float* __restrict__ Wr,
                              const float* __restrict__ br, float* __restrict__ gate,
                              int* __restrict__ idxs) {
  const int wid  = (blockIdx.x * blockDim.x + threadIdx.x) >> 6;   // token id (1 wave/token)
  const int lane = threadIdx.x & 63;
  const float* xr = x + (size_t)wid * DIM;
  double acc[8] = {0,0,0,0,0,0,0,0};
  #pragma unroll 4
  for (int j = 0; j < 16; ++j) {
    const int d = j * 64 + lane;
    const double xv = (double)xr[d];
    const float4 wa = *(const float4*)(Wr + d * 8);
    const float4 wb = *(const float4*)(Wr + d * 8 + 4);
    acc[0] += xv * (double)wa.x;  acc[1] += xv * (double)wa.y;
    acc[2] += xv * (double)wa.z;  acc[3] += xv * (double)wa.w;
    acc[4] += xv * (double)wb.x;  acc[5] += xv * (double)wb.y;
    acc[6] += xv * (double)wb.z;  acc[7] += xv * (double)wb.w;
  }
  #pragma unroll
  for (int off = 1; off < 64; off <<= 1) {
    #pragma unroll
    for (int e = 0; e < 8; ++e) acc[e] += __shfl_xor(acc[e], off);
  }
  if (lane == 0) {
    double lg[8];
    #pragma unroll
    for (int e = 0; e < 8; ++e) lg[e] = acc[e] + (double)br[e];
    int best = 0; double bm = lg[0];
    #pragma unroll
    for (int e = 1; e < 8; ++e) { if (lg[e] > bm) { bm = lg[e]; best = e; } }  // first-wins ties
    double s = 0.0;
    #pragma unroll
    for (int e = 0; e < 8; ++e) s += exp(lg[e] - bm);
    gate[wid] = (float)(1.0 / s);   // max softmax prob
    idxs[wid] = best;
  }
}

// ---------------- Ordered per-expert position scan (single block, 1024 thr, 8 tok/thr) ----
// Also: initializes slot_token to -1 (replaces a memset) and emits per-token keep flags.
__global__ void scan_kernel(const int* __restrict__ idxs, int* __restrict__ slot_token,
                            int* __restrict__ keep) {
  __shared__ int wtot[16][8];
  const int t = threadIdx.x, lane = t & 63, w = t >> 6;
  #pragma unroll
  for (int j = 0; j < 8; ++j) slot_token[t * 8 + j] = -1;   // visible after barriers below
  int myidx[8];
  #pragma unroll
  for (int j = 0; j < 8; ++j) myidx[j] = idxs[t * 8 + j];
  int cnt[8], incl[8];
  #pragma unroll
  for (int e = 0; e < 8; ++e) {
    int c = 0;
    #pragma unroll
    for (int j = 0; j < 8; ++j) c += (myidx[j] == e) ? 1 : 0;
    cnt[e] = c;
    int v = c;
    #pragma unroll
    for (int off = 1; off < 64; off <<= 1) {
      int u = __shfl_up(v, off);
      if (lane >= off) v += u;
    }
    incl[e] = v;                       // inclusive within-wave prefix
  }
  if (lane == 63) {
    #pragma unroll
    for (int e = 0; e < 8; ++e) wtot[w][e] = incl[e];
  }
  __syncthreads();
  if (t == 0) {                        // serial exclusive scan over 16 wave totals
    int run[8] = {0,0,0,0,0,0,0,0};
    for (int ww = 0; ww < 16; ++ww) {
      #pragma unroll
      for (int e = 0; e < 8; ++e) {
        int tmp = wtot[ww][e]; wtot[ww][e] = run[e]; run[e] += tmp;
      }
    }
  }
  __syncthreads();
  #pragma unroll
  for (int e = 0; e < 8; ++e) {
    int r = wtot[w][e] + incl[e] - cnt[e];   // tokens of expert e before my chunk
    #pragma unroll
    for (int j = 0; j < 8; ++j) {
      if (myidx[j] == e) {
        ++r;                                  // 1-based pos (slot 0 never used)
        const int kept = (r < CAP) ? 1 : 0;
        keep[t * 8 + j] = kept;
        if (kept) slot_token[e * CAP + r] = t * 8 + j;
      }
    }
  }
}

// ---- Gather (blocks 0..8191): Xe[slot,:] = bf16(gate[n]*x[n,:]);
// ---- ZeroFill (blocks 8192..16383): out[token,:] = 0 for dropped tokens ----
__global__ void gather_zero_kernel(const float* __restrict__ x, const float* __restrict__ gate,
                                   const int* __restrict__ slot_token,
                                   const int* __restrict__ keep,
                                   unsigned short* __restrict__ Xe,
                                   float* __restrict__ out) {
  const int t = threadIdx.x;            // 256 threads * float4 = 1024 elems
  if (blockIdx.x < NEXP * CAP) {
    const int s = blockIdx.x;
    const int n = slot_token[s];
    if (n < 0) return;                  // empty slot: row stays poison, never reaches output
    const float g = gate[n];
    const float4 v = ((const float4*)(x + (size_t)n * DIM))[t];
    ushort4 o;
    o.x = f2bf(v.x * g); o.y = f2bf(v.y * g); o.z = f2bf(v.z * g); o.w = f2bf(v.w * g);
    ((ushort4*)(Xe + (size_t)s * DIM))[t] = o;
  } else {
    const int n = blockIdx.x - NEXP * CAP;
    if (keep[n]) return;                // kept tokens fully written by gemm2 scatter
    float4 z = {0.f, 0.f, 0.f, 0.f};
    ((float4*)(out + (size_t)n * DIM))[t] = z;
  }
}

// ---------------- Weights: fp32 [K,N] -> bf16 transposed [N,K] (B^T layout), per expert ---
__global__ void wt_kernel(const float* __restrict__ W1, const float* __restrict__ W2,
                          unsigned short* __restrict__ W1T, unsigned short* __restrict__ W2T) {
  __shared__ float tile[32][33];
  const int mi = blockIdx.y;                        // 0..7: W1 expert, 8..15: W2 expert
  const int tz = blockIdx.x;
  const int tr = tz >> 5, tc = tz & 31;             // 32x32 tiles over 1024x1024
  const float* src = (mi < 8) ? (W1 + (size_t)mi * DIM * DIM)
                              : (W2 + (size_t)(mi - 8) * DIM * DIM);
  unsigned short* dst = (mi < 8) ? (W1T + (size_t)mi * DIM * DIM)
                                 : (W2T + (size_t)(mi - 8) * DIM * DIM);
  const int t = threadIdx.x;
  const int row = t >> 3;
  const int cg  = (t & 7) * 4;
  const float4 v = *(const float4*)(src + (size_t)(tr * 32 + row) * DIM + tc * 32 + cg);
  tile[row][cg + 0] = v.x; tile[row][cg + 1] = v.y;
  tile[row][cg + 2] = v.z; tile[row][cg + 3] = v.w;
  __syncthreads();
  ushort4 o;
  o.x = f2bf(tile[cg + 0][row]); o.y = f2bf(tile[cg + 1][row]);
  o.z = f2bf(tile[cg + 2][row]); o.w = f2bf(tile[cg + 3][row]);
  *(ushort4*)(dst + (size_t)(tc * 32 + row) * DIM + tr * 32 + cg) = o;
}

// ---------------- Grouped GEMM, 128x128 tile, BK=32, 16x16x32 bf16 MFMA, LDS dbuf --------
// OP==1: H = relu(Xe @ W1 + b1) -> bf16.   OP==2: out[token] = gate*(H @ W2 + b2) scatter.
template <int OP>
__global__ __launch_bounds__(256)
void gemm_kernel(const unsigned short* __restrict__ A,    // [E*CAP][DIM] bf16
                 const unsigned short* __restrict__ Bt,   // [E][DIM][DIM] bf16 (B^T rows=N)
                 const float* __restrict__ bias,          // [E][DIM]
                 const int* __restrict__ slot_token,      // OP==2
                 const float* __restrict__ gate,          // OP==2
                 unsigned short* __restrict__ Hout,       // OP==1
                 float* __restrict__ Cout)                // OP==2
{
  __shared__ unsigned short Asub[2][128 * 32];
  __shared__ unsigned short Bsub[2][128 * 32];
  const int e  = blockIdx.y;
  const int bm = blockIdx.x >> 3;
  const int bn = blockIdx.x & 7;
  const int tid = threadIdx.x, lane = tid & 63, w = tid >> 6;
  const int wr = w >> 1, wc = w & 1;

  const unsigned short* Ae = A  + (size_t)(e * CAP + bm * 128) * DIM;
  const unsigned short* Be = Bt + (size_t)e * DIM * DIM + (size_t)(bn * 128) * DIM;

  const int srow = lane >> 2;           // staging: 16 rows per 1KB chunk, 4 lanes/row
  const int scol = (lane & 3) * 8;      // 8 bf16 = 16B per lane
  const int lrow = lane & 15;
  const int kof  = (lane >> 4) * 8;

  f32x4 acc[4][4] = {};

  auto stage = [&](int buf, int kt) {
    const int k0 = kt * 32;
    #pragma unroll
    for (int c = 0; c < 2; ++c) {
      const int chunk = w + c * 4;                       // wave-uniform
      const int r = chunk * 16 + srow;
      gld_lds16(Ae + (size_t)r * DIM + k0 + scol, &Asub[buf][chunk * 512]);
      gld_lds16(Be + (size_t)r * DIM + k0 + scol, &Bsub[buf][chunk * 512]);
    }
  };
  auto compute = [&](int buf) {
    bf16x8 af[4], bfr[4];
    #pragma unroll
    for (int m = 0; m < 4; ++m)
      af[m] = *(const bf16x8*)&Asub[buf][(wr * 64 + m * 16 + lrow) * 32 + kof];
    #pragma unroll
    for (int n = 0; n < 4; ++n)
      bfr[n] = *(const bf16x8*)&Bsub[buf][(wc * 64 + n * 16 + lrow) * 32 + kof];
    #pragma unroll
    for (int m = 0; m < 4; ++m)
      #pragma unroll
      for (int n = 0; n < 4; ++n)
        acc[m][n] = __builtin_amdgcn_mfma_f32_16x16x32_bf16(af[m], bfr[n], acc[m][n], 0, 0, 0);
  };

  stage(0, 0);
  __syncthreads();                      // implicit vmcnt(0): tile 0 resident
  int cur = 0;
  for (int kt = 0; kt < 31; ++kt) {
    stage(cur ^ 1, kt + 1);             // async loads overlap with MFMA below
    compute(cur);
    __syncthreads();                    // drains vmcnt (next tile ready) + LDS reuse safety
    cur ^= 1;
  }
  compute(cur);                         // last tile, no prefetch

  if (OP == 1) {
    #pragma unroll
    for (int n = 0; n < 4; ++n) {
      const int col = bn * 128 + wc * 64 + n * 16 + lrow;
      const float bv = bias[e * DIM + col];
      #pragma unroll
      for (int m = 0; m < 4; ++m) {
        const int r0 = bm * 128 + wr * 64 + m * 16 + (lane >> 4) * 4;
        #pragma unroll
        for (int i = 0; i < 4; ++i) {
          float v = acc[m][n][i] + bv;
          v = v > 0.0f ? v : 0.0f;
          Hout[(size_t)(e * CAP + r0 + i) * DIM + col] = f2bf(v);
        }
      }
    }
  } else {
    float bv[4];
    #pragma unroll
    for (int n = 0; n < 4; ++n)
      bv[n] = bias[e * DIM + bn * 128 + wc * 64 + n * 16 + lrow];
    #pragma unroll
    for (int m = 0; m < 4; ++m) {
      const int r0 = bm * 128 + wr * 64 + m * 16 + (lane >> 4) * 4;
      #pragma unroll
      for (int i = 0; i < 4; ++i) {
        const int tok = slot_token[e * CAP + r0 + i];
        if (tok >= 0) {
          const float g = gate[tok];
          float* orow = Cout + (size_t)tok * DIM;
          #pragma unroll
          for (int n = 0; n < 4; ++n) {
            const int col = bn * 128 + wc * 64 + n * 16 + lrow;
            orow[col] = g * (acc[m][n][i] + bv[n]);
          }
        }
      }
    }
  }
}

extern "C" void kernel_launch(void* const* d_in, const int* in_sizes, int n_in,
                              void* d_out, int out_size, void* d_ws, size_t ws_size,
                              hipStream_t stream) {
  const float* x  = (const float*)d_in[0];
  const float* Wr = (const float*)d_in[1];
  const float* br = (const float*)d_in[2];
  const float* W1 = (const float*)d_in[3];
  const float* b1 = (const float*)d_in[4];
  const float* W2 = (const float*)d_in[5];
  const float* b2 = (const float*)d_in[6];
  float* out = (float*)d_out;

  char* ws = (char*)d_ws;
  unsigned short* Xe  = (unsigned short*)(ws);                                  // 16 MB
  unsigned short* Hh  = (unsigned short*)(ws + (size_t)16 * 1024 * 1024);       // 16 MB
  unsigned short* W1T = (unsigned short*)(ws + (size_t)32 * 1024 * 1024);       // 16 MB
  unsigned short* W2T = (unsigned short*)(ws + (size_t)48 * 1024 * 1024);       // 16 MB
  float* gate     = (float*)(ws + (size_t)64 * 1024 * 1024);                    // 32 KB
  int*   idxs     = (int*)  (ws + (size_t)64 * 1024 * 1024 + 32768);            // 32 KB
  int*   slot_tok = (int*)  (ws + (size_t)64 * 1024 * 1024 + 65536);            // 32 KB
  int*   keep     = (int*)  (ws + (size_t)64 * 1024 * 1024 + 98304);            // 32 KB

  router_kernel<<<2048, 256, 0, stream>>>(x, Wr, br, gate, idxs);
  scan_kernel<<<1, 1024, 0, stream>>>(idxs, slot_tok, keep);
  gather_zero_kernel<<<2 * N_TOK, 256, 0, stream>>>(x, gate, slot_tok, keep, Xe, out);
  wt_kernel<<<dim3(1024, 16), 256, 0, stream>>>(W1, W2, W1T, W2T);
  gemm_kernel<1><<<dim3(64, NEXP), 256, 0, stream>>>(Xe, W1T, b1, nullptr, nullptr, Hh, nullptr);
  gemm_kernel<2><<<dim3(64, NEXP), 256, 0, stream>>>(Hh, W2T, b2, slot_tok, gate, nullptr, out);
}

// Round 3
// 241.427 us; speedup vs baseline: 1.0310x; 1.0153x over previous
//
#include <hip/hip_runtime.h>
#include <hip/hip_bf16.h>
#include <stdint.h>

#define N_TOK 8192
#define DIM   1024
#define NEXP  8
#define CAP   1024

typedef __attribute__((ext_vector_type(8))) short bf16x8;
typedef __attribute__((ext_vector_type(4))) float f32x4;

static __device__ __forceinline__ unsigned short f2bf(float f) {
  unsigned int u = __float_as_uint(f);
  u += 0x7FFFu + ((u >> 16) & 1u);          // round-to-nearest-even
  return (unsigned short)(u >> 16);
}

// async global->LDS, 16B per lane. LDS dest must be wave-uniform base (HW adds lane*16).
static __device__ __forceinline__ void gld_lds16(const void* g, void* l) {
  __builtin_amdgcn_global_load_lds(
      (__attribute__((address_space(1))) void*)(uintptr_t)g,
      (__attribute__((address_space(3))) void*)(unsigned int)(uintptr_t)l,
      16, 0, 0);
}

// ---------------- Router: logits = x@Wr + br ; gate = max softmax prob ; idx = argmax ----
__global__ void router_kernel(const float* __restrict__ x, const float* __restrict__ Wr,
                              const float* __restrict__ br, float* __restrict__ gate,
                              int* __restrict__ idxs) {
  const int wid  = (blockIdx.x * blockDim.x + threadIdx.x) >> 6;   // token id (1 wave/token)
  const int lane = threadIdx.x & 63;
  const float* xr = x + (size_t)wid * DIM;
  double acc[8] = {0,0,0,0,0,0,0,0};
  #pragma unroll 4
  for (int j = 0; j < 16; ++j) {
    const int d = j * 64 + lane;
    const double xv = (double)xr[d];
    const float4 wa = *(const float4*)(Wr + d * 8);
    const float4 wb = *(const float4*)(Wr + d * 8 + 4);
    acc[0] += xv * (double)wa.x;  acc[1] += xv * (double)wa.y;
    acc[2] += xv * (double)wa.z;  acc[3] += xv * (double)wa.w;
    acc[4] += xv * (double)wb.x;  acc[5] += xv * (double)wb.y;
    acc[6] += xv * (double)wb.z;  acc[7] += xv * (double)wb.w;
  }
  #pragma unroll
  for (int off = 1; off < 64; off <<= 1) {
    #pragma unroll
    for (int e = 0; e < 8; ++e) acc[e] += __shfl_xor(acc[e], off);
  }
  if (lane == 0) {
    double lg[8];
    #pragma unroll
    for (int e = 0; e < 8; ++e) lg[e] = acc[e] + (double)br[e];
    int best = 0; double bm = lg[0];
    #pragma unroll
    for (int e = 1; e < 8; ++e) { if (lg[e] > bm) { bm = lg[e]; best = e; } }  // first-wins ties
    double s = 0.0;
    #pragma unroll
    for (int e = 0; e < 8; ++e) s += exp(lg[e] - bm);
    gate[wid] = (float)(1.0 / s);   // max softmax prob
    idxs[wid] = best;
  }
}

// ---------------- Ordered per-expert position scan (single block, 1024 thr, 8 tok/thr) ----
// Also: initializes slot_token to -1 (replaces a memset) and emits per-token keep flags.
__global__ void scan_kernel(const int* __restrict__ idxs, int* __restrict__ slot_token,
                            int* __restrict__ keep) {
  __shared__ int wtot[16][8];
  const int t = threadIdx.x, lane = t & 63, w = t >> 6;
  #pragma unroll
  for (int j = 0; j < 8; ++j) slot_token[t * 8 + j] = -1;   // visible after barriers below
  int myidx[8];
  #pragma unroll
  for (int j = 0; j < 8; ++j) myidx[j] = idxs[t * 8 + j];
  int cnt[8], incl[8];
  #pragma unroll
  for (int e = 0; e < 8; ++e) {
    int c = 0;
    #pragma unroll
    for (int j = 0; j < 8; ++j) c += (myidx[j] == e) ? 1 : 0;
    cnt[e] = c;
    int v = c;
    #pragma unroll
    for (int off = 1; off < 64; off <<= 1) {
      int u = __shfl_up(v, off);
      if (lane >= off) v += u;
    }
    incl[e] = v;                       // inclusive within-wave prefix
  }
  if (lane == 63) {
    #pragma unroll
    for (int e = 0; e < 8; ++e) wtot[w][e] = incl[e];
  }
  __syncthreads();
  if (t == 0) {                        // serial exclusive scan over 16 wave totals
    int run[8] = {0,0,0,0,0,0,0,0};
    for (int ww = 0; ww < 16; ++ww) {
      #pragma unroll
      for (int e = 0; e < 8; ++e) {
        int tmp = wtot[ww][e]; wtot[ww][e] = run[e]; run[e] += tmp;
      }
    }
  }
  __syncthreads();
  #pragma unroll
  for (int e = 0; e < 8; ++e) {
    int r = wtot[w][e] + incl[e] - cnt[e];   // tokens of expert e before my chunk
    #pragma unroll
    for (int j = 0; j < 8; ++j) {
      if (myidx[j] == e) {
        ++r;                                  // 1-based pos (slot 0 never used)
        const int kept = (r < CAP) ? 1 : 0;
        keep[t * 8 + j] = kept;
        if (kept) slot_token[e * CAP + r] = t * 8 + j;
      }
    }
  }
}

// ---- Gather (blocks 0..8191): Xe[slot,:] = bf16(gate[n]*x[n,:]);
// ---- ZeroFill (blocks 8192..16383): out[token,:] = 0 for dropped tokens ----
__global__ void gather_zero_kernel(const float* __restrict__ x, const float* __restrict__ gate,
                                   const int* __restrict__ slot_token,
                                   const int* __restrict__ keep,
                                   unsigned short* __restrict__ Xe,
                                   float* __restrict__ out) {
  const int t = threadIdx.x;            // 256 threads * float4 = 1024 elems
  if (blockIdx.x < NEXP * CAP) {
    const int s = blockIdx.x;
    const int n = slot_token[s];
    if (n < 0) return;                  // empty slot: row stays poison, never reaches output
    const float g = gate[n];
    const float4 v = ((const float4*)(x + (size_t)n * DIM))[t];
    ushort4 o;
    o.x = f2bf(v.x * g); o.y = f2bf(v.y * g); o.z = f2bf(v.z * g); o.w = f2bf(v.w * g);
    ((ushort4*)(Xe + (size_t)s * DIM))[t] = o;
  } else {
    const int n = blockIdx.x - NEXP * CAP;
    if (keep[n]) return;                // kept tokens fully written by gemm2 scatter
    float4 z = {0.f, 0.f, 0.f, 0.f};
    ((float4*)(out + (size_t)n * DIM))[t] = z;
  }
}

// ---------------- Weights: fp32 [K,N] -> bf16 transposed [N,K] (B^T layout), per expert ---
__global__ void wt_kernel(const float* __restrict__ W1, const float* __restrict__ W2,
                          unsigned short* __restrict__ W1T, unsigned short* __restrict__ W2T) {
  __shared__ float tile[32][33];
  const int mi = blockIdx.y;                        // 0..7: W1 expert, 8..15: W2 expert
  const int tz = blockIdx.x;
  const int tr = tz >> 5, tc = tz & 31;             // 32x32 tiles over 1024x1024
  const float* src = (mi < 8) ? (W1 + (size_t)mi * DIM * DIM)
                              : (W2 + (size_t)(mi - 8) * DIM * DIM);
  unsigned short* dst = (mi < 8) ? (W1T + (size_t)mi * DIM * DIM)
                                 : (W2T + (size_t)(mi - 8) * DIM * DIM);
  const int t = threadIdx.x;
  const int row = t >> 3;
  const int cg  = (t & 7) * 4;
  const float4 v = *(const float4*)(src + (size_t)(tr * 32 + row) * DIM + tc * 32 + cg);
  tile[row][cg + 0] = v.x; tile[row][cg + 1] = v.y;
  tile[row][cg + 2] = v.z; tile[row][cg + 3] = v.w;
  __syncthreads();
  ushort4 o;
  o.x = f2bf(tile[cg + 0][row]); o.y = f2bf(tile[cg + 1][row]);
  o.z = f2bf(tile[cg + 2][row]); o.w = f2bf(tile[cg + 3][row]);
  *(ushort4*)(dst + (size_t)(tc * 32 + row) * DIM + tr * 32 + cg) = o;
}

// ---------------- Grouped GEMM, 128x128 tile, BK=32, 16x16x32 bf16 MFMA, LDS dbuf --------
// Flat 512-block grid; e = bid & 7 so each expert's 64 blocks land on one XCD (bid%8
// round-robin) -> that expert's A panel (2MB) + B panel (2MB) stay resident in its 4MB L2.
// OP==1: H = relu(Xe @ W1 + b1) -> bf16.   OP==2: out[token] = gate*(H @ W2 + b2) scatter.
template <int OP>
__global__ __launch_bounds__(256)
void gemm_kernel(const unsigned short* __restrict__ A,    // [E*CAP][DIM] bf16
                 const unsigned short* __restrict__ Bt,   // [E][DIM][DIM] bf16 (B^T rows=N)
                 const float* __restrict__ bias,          // [E][DIM]
                 const int* __restrict__ slot_token,      // OP==2
                 const float* __restrict__ gate,          // OP==2
                 unsigned short* __restrict__ Hout,       // OP==1
                 float* __restrict__ Cout)                // OP==2
{
  __shared__ unsigned short Asub[2][128 * 32];
  __shared__ unsigned short Bsub[2][128 * 32];
  const int bid = blockIdx.x;
  const int e  = bid & 7;               // expert == XCD (bid%8 round-robin heuristic)
  const int tt = bid >> 3;              // 0..63 tile index within expert
  const int bm = tt >> 3;
  const int bn = tt & 7;
  const int tid = threadIdx.x, lane = tid & 63, w = tid >> 6;
  const int wr = w >> 1, wc = w & 1;

  const unsigned short* Ae = A  + (size_t)(e * CAP + bm * 128) * DIM;
  const unsigned short* Be = Bt + (size_t)e * DIM * DIM + (size_t)(bn * 128) * DIM;

  const int srow = lane >> 2;           // staging: 16 rows per 1KB chunk, 4 lanes/row
  const int scol = (lane & 3) * 8;      // 8 bf16 = 16B per lane
  const int lrow = lane & 15;
  const int kof  = (lane >> 4) * 8;

  f32x4 acc[4][4] = {};

  auto stage = [&](int buf, int kt) {
    const int k0 = kt * 32;
    #pragma unroll
    for (int c = 0; c < 2; ++c) {
      const int chunk = w + c * 4;                       // wave-uniform
      const int r = chunk * 16 + srow;
      gld_lds16(Ae + (size_t)r * DIM + k0 + scol, &Asub[buf][chunk * 512]);
      gld_lds16(Be + (size_t)r * DIM + k0 + scol, &Bsub[buf][chunk * 512]);
    }
  };
  auto compute = [&](int buf) {
    bf16x8 af[4], bfr[4];
    #pragma unroll
    for (int m = 0; m < 4; ++m)
      af[m] = *(const bf16x8*)&Asub[buf][(wr * 64 + m * 16 + lrow) * 32 + kof];
    #pragma unroll
    for (int n = 0; n < 4; ++n)
      bfr[n] = *(const bf16x8*)&Bsub[buf][(wc * 64 + n * 16 + lrow) * 32 + kof];
    #pragma unroll
    for (int m = 0; m < 4; ++m)
      #pragma unroll
      for (int n = 0; n < 4; ++n)
        acc[m][n] = __builtin_amdgcn_mfma_f32_16x16x32_bf16(af[m], bfr[n], acc[m][n], 0, 0, 0);
  };

  stage(0, 0);
  __syncthreads();                      // implicit vmcnt(0): tile 0 resident
  int cur = 0;
  for (int kt = 0; kt < 31; ++kt) {
    stage(cur ^ 1, kt + 1);             // async loads overlap with MFMA below
    compute(cur);
    __syncthreads();                    // drains vmcnt (next tile ready) + LDS reuse safety
    cur ^= 1;
  }
  compute(cur);                         // last tile, no prefetch

  if (OP == 1) {
    #pragma unroll
    for (int n = 0; n < 4; ++n) {
      const int col = bn * 128 + wc * 64 + n * 16 + lrow;
      const float bv = bias[e * DIM + col];
      #pragma unroll
      for (int m = 0; m < 4; ++m) {
        const int r0 = bm * 128 + wr * 64 + m * 16 + (lane >> 4) * 4;
        #pragma unroll
        for (int i = 0; i < 4; ++i) {
          float v = acc[m][n][i] + bv;
          v = v > 0.0f ? v : 0.0f;
          Hout[(size_t)(e * CAP + r0 + i) * DIM + col] = f2bf(v);
        }
      }
    }
  } else {
    float bv[4];
    #pragma unroll
    for (int n = 0; n < 4; ++n)
      bv[n] = bias[e * DIM + bn * 128 + wc * 64 + n * 16 + lrow];
    #pragma unroll
    for (int m = 0; m < 4; ++m) {
      const int r0 = bm * 128 + wr * 64 + m * 16 + (lane >> 4) * 4;
      #pragma unroll
      for (int i = 0; i < 4; ++i) {
        const int tok = slot_token[e * CAP + r0 + i];
        if (tok >= 0) {
          const float g = gate[tok];
          float* orow = Cout + (size_t)tok * DIM;
          #pragma unroll
          for (int n = 0; n < 4; ++n) {
            const int col = bn * 128 + wc * 64 + n * 16 + lrow;
            orow[col] = g * (acc[m][n][i] + bv[n]);
          }
        }
      }
    }
  }
}

extern "C" void kernel_launch(void* const* d_in, const int* in_sizes, int n_in,
                              void* d_out, int out_size, void* d_ws, size_t ws_size,
                              hipStream_t stream) {
  const float* x  = (const float*)d_in[0];
  const float* Wr = (const float*)d_in[1];
  const float* br = (const float*)d_in[2];
  const float* W1 = (const float*)d_in[3];
  const float* b1 = (const float*)d_in[4];
  const float* W2 = (const float*)d_in[5];
  const float* b2 = (const float*)d_in[6];
  float* out = (float*)d_out;

  char* ws = (char*)d_ws;
  unsigned short* Xe  = (unsigned short*)(ws);                                  // 16 MB
  unsigned short* Hh  = (unsigned short*)(ws + (size_t)16 * 1024 * 1024);       // 16 MB
  unsigned short* W1T = (unsigned short*)(ws + (size_t)32 * 1024 * 1024);       // 16 MB
  unsigned short* W2T = (unsigned short*)(ws + (size_t)48 * 1024 * 1024);       // 16 MB
  float* gate     = (float*)(ws + (size_t)64 * 1024 * 1024);                    // 32 KB
  int*   idxs     = (int*)  (ws + (size_t)64 * 1024 * 1024 + 32768);            // 32 KB
  int*   slot_tok = (int*)  (ws + (size_t)64 * 1024 * 1024 + 65536);            // 32 KB
  int*   keep     = (int*)  (ws + (size_t)64 * 1024 * 1024 + 98304);            // 32 KB

  router_kernel<<<2048, 256, 0, stream>>>(x, Wr, br, gate, idxs);
  scan_kernel<<<1, 1024, 0, stream>>>(idxs, slot_tok, keep);
  gather_zero_kernel<<<2 * N_TOK, 256, 0, stream>>>(x, gate, slot_tok, keep, Xe, out);
  wt_kernel<<<dim3(1024, 16), 256, 0, stream>>>(W1, W2, W1T, W2T);
  gemm_kernel<1><<<512, 256, 0, stream>>>(Xe, W1T, b1, nullptr, nullptr, Hh, nullptr);
  gemm_kernel<2><<<512, 256, 0, stream>>>(Hh, W2T, b2, slot_tok, gate, nullptr, out);
}

// Round 5
// 234.871 us; speedup vs baseline: 1.0598x; 1.0279x over previous
//
#include <hip/hip_runtime.h>
#include <hip/hip_bf16.h>
#include <stdint.h>

#define N_TOK 8192
#define DIM   1024
#define NEXP  8
#define CAP   1024

typedef __attribute__((ext_vector_type(8))) short bf16x8;
typedef __attribute__((ext_vector_type(4))) float f32x4;

static __device__ __forceinline__ unsigned short f2bf(float f) {
  unsigned int u = __float_as_uint(f);
  u += 0x7FFFu + ((u >> 16) & 1u);          // round-to-nearest-even
  return (unsigned short)(u >> 16);
}

// async global->LDS, 16B per lane. LDS dest must be wave-uniform base (HW adds lane*16).
static __device__ __forceinline__ void gld_lds16(const void* g, void* l) {
  __builtin_amdgcn_global_load_lds(
      (__attribute__((address_space(1))) void*)(uintptr_t)g,
      (__attribute__((address_space(3))) void*)(unsigned int)(uintptr_t)l,
      16, 0, 0);
}

// ---------------- Router: logits = x@Wr + br ; gate = max softmax prob ; idx = argmax ----
__global__ void router_kernel(const float* __restrict__ x, const float* __restrict__ Wr,
                              const float* __restrict__ br, float* __restrict__ gate,
                              int* __restrict__ idxs) {
  const int wid  = (blockIdx.x * blockDim.x + threadIdx.x) >> 6;   // token id (1 wave/token)
  const int lane = threadIdx.x & 63;
  const float* xr = x + (size_t)wid * DIM;
  double acc[8] = {0,0,0,0,0,0,0,0};
  #pragma unroll 4
  for (int j = 0; j < 16; ++j) {
    const int d = j * 64 + lane;
    const double xv = (double)xr[d];
    const float4 wa = *(const float4*)(Wr + d * 8);
    const float4 wb = *(const float4*)(Wr + d * 8 + 4);
    acc[0] += xv * (double)wa.x;  acc[1] += xv * (double)wa.y;
    acc[2] += xv * (double)wa.z;  acc[3] += xv * (double)wa.w;
    acc[4] += xv * (double)wb.x;  acc[5] += xv * (double)wb.y;
    acc[6] += xv * (double)wb.z;  acc[7] += xv * (double)wb.w;
  }
  #pragma unroll
  for (int off = 1; off < 64; off <<= 1) {
    #pragma unroll
    for (int e = 0; e < 8; ++e) acc[e] += __shfl_xor(acc[e], off);
  }
  if (lane == 0) {
    double lg[8];
    #pragma unroll
    for (int e = 0; e < 8; ++e) lg[e] = acc[e] + (double)br[e];
    int best = 0; double bm = lg[0];
    #pragma unroll
    for (int e = 1; e < 8; ++e) { if (lg[e] > bm) { bm = lg[e]; best = e; } }  // first-wins ties
    double s = 0.0;
    #pragma unroll
    for (int e = 0; e < 8; ++e) s += exp(lg[e] - bm);
    gate[wid] = (float)(1.0 / s);   // max softmax prob
    idxs[wid] = best;
  }
}

// ---------------- Ordered per-expert position scan (single block, 1024 thr, 8 tok/thr) ----
// Also: initializes slot_token to -1 (replaces a memset) and emits per-token keep flags.
__global__ void scan_kernel(const int* __restrict__ idxs, int* __restrict__ slot_token,
                            int* __restrict__ keep) {
  __shared__ int wtot[16][8];
  const int t = threadIdx.x, lane = t & 63, w = t >> 6;
  #pragma unroll
  for (int j = 0; j < 8; ++j) slot_token[t * 8 + j] = -1;   // visible after barriers below
  int myidx[8];
  #pragma unroll
  for (int j = 0; j < 8; ++j) myidx[j] = idxs[t * 8 + j];
  int cnt[8], incl[8];
  #pragma unroll
  for (int e = 0; e < 8; ++e) {
    int c = 0;
    #pragma unroll
    for (int j = 0; j < 8; ++j) c += (myidx[j] == e) ? 1 : 0;
    cnt[e] = c;
    int v = c;
    #pragma unroll
    for (int off = 1; off < 64; off <<= 1) {
      int u = __shfl_up(v, off);
      if (lane >= off) v += u;
    }
    incl[e] = v;                       // inclusive within-wave prefix
  }
  if (lane == 63) {
    #pragma unroll
    for (int e = 0; e < 8; ++e) wtot[w][e] = incl[e];
  }
  __syncthreads();
  if (t == 0) {                        // serial exclusive scan over 16 wave totals
    int run[8] = {0,0,0,0,0,0,0,0};
    for (int ww = 0; ww < 16; ++ww) {
      #pragma unroll
      for (int e = 0; e < 8; ++e) {
        int tmp = wtot[ww][e]; wtot[ww][e] = run[e]; run[e] += tmp;
      }
    }
  }
  __syncthreads();
  #pragma unroll
  for (int e = 0; e < 8; ++e) {
    int r = wtot[w][e] + incl[e] - cnt[e];   // tokens of expert e before my chunk
    #pragma unroll
    for (int j = 0; j < 8; ++j) {
      if (myidx[j] == e) {
        ++r;                                  // 1-based pos (slot 0 never used)
        const int kept = (r < CAP) ? 1 : 0;
        keep[t * 8 + j] = kept;
        if (kept) slot_token[e * CAP + r] = t * 8 + j;
      }
    }
  }
}

// ---- Fused utility kernel (one launch, three independent BW-bound phases):
//   blocks [0, 16384):          weight fp32 [K,N] -> bf16 transposed [N,K] (B^T layout)
//   blocks [16384, 24576):      gather Xe[slot,:] = bf16(gate[n]*x[n,:])
//   blocks [24576, 32768):      zero-fill out rows of dropped tokens
__global__ void util_kernel(const float* __restrict__ W1, const float* __restrict__ W2,
                            unsigned short* __restrict__ W1T, unsigned short* __restrict__ W2T,
                            const float* __restrict__ x, const float* __restrict__ gate,
                            const int* __restrict__ slot_token, const int* __restrict__ keep,
                            unsigned short* __restrict__ Xe, float* __restrict__ out) {
  const int t = threadIdx.x;
  if (blockIdx.x < 16384) {
    __shared__ float tile[32][33];
    const int mi = blockIdx.x >> 10;                  // 0..7: W1 expert, 8..15: W2 expert
    const int tz = blockIdx.x & 1023;
    const int tr = tz >> 5, tc = tz & 31;             // 32x32 tiles over 1024x1024
    const float* src = (mi < 8) ? (W1 + (size_t)mi * DIM * DIM)
                                : (W2 + (size_t)(mi - 8) * DIM * DIM);
    unsigned short* dst = (mi < 8) ? (W1T + (size_t)mi * DIM * DIM)
                                   : (W2T + (size_t)(mi - 8) * DIM * DIM);
    const int row = t >> 3;
    const int cg  = (t & 7) * 4;
    const float4 v = *(const float4*)(src + (size_t)(tr * 32 + row) * DIM + tc * 32 + cg);
    tile[row][cg + 0] = v.x; tile[row][cg + 1] = v.y;
    tile[row][cg + 2] = v.z; tile[row][cg + 3] = v.w;
    __syncthreads();
    ushort4 o;
    o.x = f2bf(tile[cg + 0][row]); o.y = f2bf(tile[cg + 1][row]);
    o.z = f2bf(tile[cg + 2][row]); o.w = f2bf(tile[cg + 3][row]);
    *(ushort4*)(dst + (size_t)(tc * 32 + row) * DIM + tr * 32 + cg) = o;
  } else if (blockIdx.x < 16384 + NEXP * CAP) {
    const int s = blockIdx.x - 16384;
    const int n = slot_token[s];
    if (n < 0) return;                  // empty slot: row stays poison, never reaches output
    const float g = gate[n];
    const float4 v = ((const float4*)(x + (size_t)n * DIM))[t];
    ushort4 o;
    o.x = f2bf(v.x * g); o.y = f2bf(v.y * g); o.z = f2bf(v.z * g); o.w = f2bf(v.w * g);
    ((ushort4*)(Xe + (size_t)s * DIM))[t] = o;
  } else {
    const int n = blockIdx.x - (16384 + NEXP * CAP);
    if (keep[n]) return;                // kept tokens fully written by gemm2 scatter
    float4 z = {0.f, 0.f, 0.f, 0.f};
    ((float4*)(out + (size_t)n * DIM))[t] = z;
  }
}

// ---------------- Grouped GEMM, 128x128 tile, BK=32, 16x16x32 bf16 MFMA ------------------
// 3-buffer LDS ring with counted s_waitcnt vmcnt(4) + raw s_barrier: tile k+2 is issued
// while computing tile k; vmcnt never drained to 0 in the main loop (T3/T4-lite, m201
// pattern). e = bid&7 pins each expert's 64 blocks to one XCD (L2 residency).
// OP==1: H = relu(Xe @ W1 + b1) -> bf16.   OP==2: out[token] = gate*(H @ W2 + b2) scatter.
template <int OP>
__global__ __launch_bounds__(256)
void gemm_kernel(const unsigned short* __restrict__ A,    // [E*CAP][DIM] bf16
                 const unsigned short* __restrict__ Bt,   // [E][DIM][DIM] bf16 (B^T rows=N)
                 const float* __restrict__ bias,          // [E][DIM]
                 const int* __restrict__ slot_token,      // OP==2
                 const float* __restrict__ gate,          // OP==2
                 unsigned short* __restrict__ Hout,       // OP==1
                 float* __restrict__ Cout)                // OP==2
{
  __shared__ unsigned short Asub[3][128 * 32];
  __shared__ unsigned short Bsub[3][128 * 32];
  const int bid = blockIdx.x;
  const int e  = bid & 7;               // expert == XCD (bid%8 round-robin heuristic)
  const int tt = bid >> 3;              // 0..63 tile index within expert
  const int bm = tt >> 3;
  const int bn = tt & 7;
  const int tid = threadIdx.x, lane = tid & 63, w = tid >> 6;
  const int wr = w >> 1, wc = w & 1;

  const unsigned short* Ae = A  + (size_t)(e * CAP + bm * 128) * DIM;
  const unsigned short* Be = Bt + (size_t)e * DIM * DIM + (size_t)(bn * 128) * DIM;

  const int srow = lane >> 2;           // staging: 16 rows per 1KB chunk, 4 lanes/row
  const int scol = (lane & 3) * 8;      // 8 bf16 = 16B per lane
  const int lrow = lane & 15;
  const int kof  = (lane >> 4) * 8;

  f32x4 acc[4][4] = {};

  auto stage = [&](int buf, int kt) {   // 4 gld_lds per wave (2 A + 2 B)
    const int k0 = kt * 32;
    #pragma unroll
    for (int c = 0; c < 2; ++c) {
      const int chunk = w + c * 4;                       // wave-uniform
      const int r = chunk * 16 + srow;
      gld_lds16(Ae + (size_t)r * DIM + k0 + scol, &Asub[buf][chunk * 512]);
      gld_lds16(Be + (size_t)r * DIM + k0 + scol, &Bsub[buf][chunk * 512]);
    }
  };
  auto compute = [&](int buf) {
    bf16x8 af[4], bfr[4];
    #pragma unroll
    for (int m = 0; m < 4; ++m)
      af[m] = *(const bf16x8*)&Asub[buf][(wr * 64 + m * 16 + lrow) * 32 + kof];
    #pragma unroll
    for (int n = 0; n < 4; ++n)
      bfr[n] = *(const bf16x8*)&Bsub[buf][(wc * 64 + n * 16 + lrow) * 32 + kof];
    #pragma unroll
    for (int m = 0; m < 4; ++m)
      #pragma unroll
      for (int n = 0; n < 4; ++n)
        acc[m][n] = __builtin_amdgcn_mfma_f32_16x16x32_bf16(af[m], bfr[n], acc[m][n], 0, 0, 0);
  };

  stage(0, 0);                          // 4 outstanding
  stage(1, 1);                          // 8 outstanding
  asm volatile("s_waitcnt vmcnt(4)" ::: "memory");   // tile 0 (my 4 oldest) in LDS
  __builtin_amdgcn_s_barrier();                      // everyone's tile 0 in LDS
  int b0 = 0, b1 = 1, b2 = 2;
  for (int kt = 0; kt < 32; ++kt) {
    if (kt < 30) stage(b2, kt + 2);     // issue next-next tile into the free buffer
    compute(b0);                        // consume certified tile kt
    if (kt == 31) break;
    if (kt < 30) asm volatile("s_waitcnt vmcnt(4)" ::: "memory");  // tile kt+1 (mine) done
    else         asm volatile("s_waitcnt vmcnt(0)" ::: "memory");  // tail drain
    __builtin_amdgcn_s_barrier();       // everyone done reading b0 + tile kt+1 resident
    const int tb = b0; b0 = b1; b1 = b2; b2 = tb;     // rotate ring
  }

  if (OP == 1) {
    #pragma unroll
    for (int n = 0; n < 4; ++n) {
      const int col = bn * 128 + wc * 64 + n * 16 + lrow;
      const float bv = bias[e * DIM + col];
      #pragma unroll
      for (int m = 0; m < 4; ++m) {
        const int r0 = bm * 128 + wr * 64 + m * 16 + (lane >> 4) * 4;
        #pragma unroll
        for (int i = 0; i < 4; ++i) {
          float v = acc[m][n][i] + bv;
          v = v > 0.0f ? v : 0.0f;
          Hout[(size_t)(e * CAP + r0 + i) * DIM + col] = f2bf(v);
        }
      }
    }
  } else {
    float bv[4];
    #pragma unroll
    for (int n = 0; n < 4; ++n)
      bv[n] = bias[e * DIM + bn * 128 + wc * 64 + n * 16 + lrow];
    #pragma unroll
    for (int m = 0; m < 4; ++m) {
      const int r0 = bm * 128 + wr * 64 + m * 16 + (lane >> 4) * 4;
      #pragma unroll
      for (int i = 0; i < 4; ++i) {
        const int tok = slot_token[e * CAP + r0 + i];
        if (tok >= 0) {
          const float g = gate[tok];
          float* orow = Cout + (size_t)tok * DIM;
          #pragma unroll
          for (int n = 0; n < 4; ++n) {
            const int col = bn * 128 + wc * 64 + n * 16 + lrow;
            orow[col] = g * (acc[m][n][i] + bv[n]);
          }
        }
      }
    }
  }
}

extern "C" void kernel_launch(void* const* d_in, const int* in_sizes, int n_in,
                              void* d_out, int out_size, void* d_ws, size_t ws_size,
                              hipStream_t stream) {
  const float* x  = (const float*)d_in[0];
  const float* Wr = (const float*)d_in[1];
  const float* br = (const float*)d_in[2];
  const float* W1 = (const float*)d_in[3];
  const float* b1 = (const float*)d_in[4];
  const float* W2 = (const float*)d_in[5];
  const float* b2 = (const float*)d_in[6];
  float* out = (float*)d_out;

  char* ws = (char*)d_ws;
  unsigned short* Xe  = (unsigned short*)(ws);                                  // 16 MB
  unsigned short* Hh  = (unsigned short*)(ws + (size_t)16 * 1024 * 1024);       // 16 MB
  unsigned short* W1T = (unsigned short*)(ws + (size_t)32 * 1024 * 1024);       // 16 MB
  unsigned short* W2T = (unsigned short*)(ws + (size_t)48 * 1024 * 1024);       // 16 MB
  float* gate     = (float*)(ws + (size_t)64 * 1024 * 1024);                    // 32 KB
  int*   idxs     = (int*)  (ws + (size_t)64 * 1024 * 1024 + 32768);            // 32 KB
  int*   slot_tok = (int*)  (ws + (size_t)64 * 1024 * 1024 + 65536);            // 32 KB
  int*   keep     = (int*)  (ws + (size_t)64 * 1024 * 1024 + 98304);            // 32 KB

  router_kernel<<<2048, 256, 0, stream>>>(x, Wr, br, gate, idxs);
  scan_kernel<<<1, 1024, 0, stream>>>(idxs, slot_tok, keep);
  util_kernel<<<32768, 256, 0, stream>>>(W1, W2, W1T, W2T, x, gate, slot_tok, keep, Xe, out);
  gemm_kernel<1><<<512, 256, 0, stream>>>(Xe, W1T, b1, nullptr, nullptr, Hh, nullptr);
  gemm_kernel<2><<<512, 256, 0, stream>>>(Hh, W2T, b2, slot_tok, gate, nullptr, out);
}